// Round 3
// baseline (32999.640 us; speedup 1.0000x reference)
//
#include <hip/hip_runtime.h>

// ============================================================================
// 3-layer stacked LSTM (T=2048), MI355X — round 3.
// Wave-autonomous recurrence: NO __syncthreads inside the LSTM step loops.
// Each wave polls tagged (f32,tag) u64 h-values, stages them in wave-private
// LDS (in-order DS pipe => no barrier), FMA-reduces in registers, gathers
// gates via shfl, and 4/16 lanes store tagged h(t). Double-buffered by t&1.
// ============================================================================

#define T_STEPS 2048

using f4v   = __attribute__((ext_vector_type(4))) float;
using s8v   = __attribute__((ext_vector_type(8))) short;
using u16x8 = __attribute__((ext_vector_type(8))) unsigned short;

union HU { unsigned long long u; unsigned v[2]; float f[2]; };

__device__ __forceinline__ unsigned short f2bf(float v) {
  unsigned u = __float_as_uint(v);
  u = (u + 0x7FFFu + ((u >> 16) & 1u)) >> 16;   // RNE
  return (unsigned short)u;
}
__device__ __forceinline__ float bf2f(unsigned short b) {
  return __uint_as_float(((unsigned)b) << 16);
}
__device__ __forceinline__ float sigm(float x) { return 1.0f / (1.0f + __expf(-x)); }
__device__ __forceinline__ float tanh_f(float x) {
  float ax = fabsf(x);
  float e = __expf(-2.0f * ax);
  float t = (1.0f - e) / (1.0f + e);
  return copysignf(t, x);
}
__device__ __forceinline__ unsigned long long ld_agent(const unsigned long long* p) {
  return __hip_atomic_load(p, __ATOMIC_RELAXED, __HIP_MEMORY_SCOPE_AGENT);
}
__device__ __forceinline__ void st_agent(unsigned long long* p, unsigned long long v) {
  __hip_atomic_store(p, v, __ATOMIC_RELAXED, __HIP_MEMORY_SCOPE_AGENT);
}
__device__ __forceinline__ void store_tagged(unsigned long long* p, float v, unsigned tag) {
  HU c; c.f[0] = v; c.v[1] = tag;
  st_agent(p, c.u);
}

// Poll N consecutive tagged u64 until all tags >= tgt; return stripped f32s.
template <int N_>
__device__ __forceinline__ void pollN(const unsigned long long* p, unsigned tgt,
                                      float* out) {
  HU c[N_];
#pragma unroll
  for (int k = 0; k < N_; ++k) c[k].u = ld_agent(p + k);
  unsigned n = 0;
  for (;;) {
    bool ok = true;
#pragma unroll
    for (int k = 0; k < N_; ++k) ok &= (c[k].v[1] >= tgt);
    if (ok || ++n > (1u << 20)) break;        // parachute against deadlock
#pragma unroll
    for (int k = 0; k < N_; ++k) c[k].u = ld_agent(p + k);
  }
#pragma unroll
  for (int k = 0; k < N_; ++k) out[k] = c[k].f[0];
}

// ============================================================================
// lstm1: 21 channels x H=256, shared weights. 84 WGs (4/channel) x 256 thr.
// Wave owns 16 units; lane = (gate g=lane>>4, unit u16=lane&15) = 1 full row:
// 256 Whh + 64 Wih f32 in regs. Poll 4 tagged h per lane (covers channel's
// 256). Fused input projection; x(t+1) prefetched. No barriers.
// ============================================================================
__global__ __launch_bounds__(256, 1) void lstm1_kernel(
    const float* __restrict__ x,     // [2048,64,21]
    const float* __restrict__ Wih,   // [1024,64]
    const float* __restrict__ Whh,   // [1024,256]
    const float* __restrict__ bih, const float* __restrict__ bhh,
    unsigned long long* __restrict__ hg,   // [2][21*256] tagged
    unsigned short* __restrict__ h1hi, unsigned short* __restrict__ h1lo) // [2048,5376]
{
  const int c = blockIdx.x >> 2;
  const int widx = threadIdx.x >> 6;
  const int lane = threadIdx.x & 63;
  const int wv = ((blockIdx.x & 3) << 2) | widx;   // 0..15
  const int u16 = lane & 15, g = lane >> 4;
  const int unit = 16 * wv + u16;
  const int grow = g * 256 + unit;

  f4v wh4[64], wx4[16];
  const f4v* wsrc = (const f4v*)(Whh + (size_t)grow * 256);
#pragma unroll
  for (int j = 0; j < 64; ++j) wh4[j] = wsrc[j];
  const f4v* xsrc = (const f4v*)(Wih + (size_t)grow * 64);
#pragma unroll
  for (int j = 0; j < 16; ++j) wx4[j] = xsrc[j];
  const float bias = bih[grow] + bhh[grow];

  __shared__ __align__(16) float hws[4 * 336];     // per wave: h[256] + x[64]
  float* const reg0 = &hws[widx * 336];

  float cst = 0.0f;
  float xpre = x[(size_t)lane * 21 + c];
  const unsigned long long* hgc = hg + c * 256;

  for (int t = 0; t < T_STEPS; ++t) {
    reg0[256 + lane] = xpre;                       // stage x(t)
    if (t + 1 < T_STEPS) xpre = x[(size_t)(t + 1) * 1344 + lane * 21 + c];
    float hv[4];
    pollN<4>(hgc + ((size_t)((t + 1) & 1)) * 5376 + 4 * lane, (unsigned)t, hv);
    *(f4v*)&reg0[4 * lane] = f4v{hv[0], hv[1], hv[2], hv[3]};
    float a0 = 0, a1 = 0, a2 = 0, a3 = 0;
#pragma unroll
    for (int j = 0; j < 64; ++j) {
      f4v h4 = *(const f4v*)&reg0[4 * j];          // all-lane broadcast read
      a0 = fmaf(wh4[j][0], h4[0], a0);
      a1 = fmaf(wh4[j][1], h4[1], a1);
      a2 = fmaf(wh4[j][2], h4[2], a2);
      a3 = fmaf(wh4[j][3], h4[3], a3);
    }
#pragma unroll
    for (int j = 0; j < 16; ++j) {
      f4v x4 = *(const f4v*)&reg0[256 + 4 * j];
      a0 = fmaf(wx4[j][0], x4[0], a0);
      a1 = fmaf(wx4[j][1], x4[1], a1);
      a2 = fmaf(wx4[j][2], x4[2], a2);
      a3 = fmaf(wx4[j][3], x4[3], a3);
    }
    float z = (a0 + a1) + (a2 + a3) + bias;
    float zi = __shfl(z, u16);
    float zf = __shfl(z, 16 + u16);
    float zg = __shfl(z, 32 + u16);
    float zo = __shfl(z, 48 + u16);
    if (lane < 16) {
      float cn = sigm(zf) * cst + sigm(zi) * tanh_f(zg);
      float hn = sigm(zo) * tanh_f(cn);
      cst = cn;
      int hidx = c * 256 + 16 * wv + lane;
      store_tagged(&hg[((size_t)(t & 1)) * 5376 + hidx], hn, (unsigned)(t + 1));
      unsigned short hb = f2bf(hn);
      h1hi[(size_t)t * 5376 + hidx] = hb;
      h1lo[(size_t)t * 5376 + hidx] = f2bf(hn - bf2f(hb));
    }
  }
}

// ============================================================================
// lstm2: H2=1024. 64 WGs x 256 thr = 256 waves; wave owns 4 units.
// lane = (u=lane&3, g=(lane>>2)&3, q=lane>>4): quarter-row (256 f32) in regs.
// Lane polls h[16*lane..+15] (== its quarter's slice) -> wave-private skewed
// LDS -> broadcast FMA -> shfl_xor(16,32) q-reduce -> +xw -> shfl gather.
// ============================================================================
__global__ __launch_bounds__(256, 1) void lstm2_kernel(
    const float* __restrict__ Whh,   // [4096,1024]
    const float* __restrict__ xw,    // [2048,4096] bias pre-folded
    unsigned long long* __restrict__ hg,   // [2][1024] tagged
    unsigned short* __restrict__ hhi, unsigned short* __restrict__ hlo)  // [2048,1024]
{
  const int widx = threadIdx.x >> 6, lane = threadIdx.x & 63;
  const int gw = blockIdx.x * 4 + widx;          // 0..255
  const int u = lane & 3, g = (lane >> 2) & 3, q = lane >> 4;
  const int grow = g * 1024 + 4 * gw + u;

  f4v wh4[64];
  const f4v* wsrc = (const f4v*)(Whh + (size_t)grow * 1024 + q * 256);
#pragma unroll
  for (int j = 0; j < 64; ++j) wh4[j] = wsrc[j];

  // per-wave region 1056 f32; quarter q at +q*260 (bank skew 4q)
  __shared__ __align__(16) float hws[4 * 1056];
  float* const qreg = &hws[widx * 1056 + q * 260];
  float* const wreg = qreg + (lane & 15) * 16;

  float cst = 0.0f;
  float xwv = xw[grow];

  for (int t = 0; t < T_STEPS; ++t) {
    float xwn = 0.0f;
    if (t + 1 < T_STEPS) xwn = xw[(size_t)(t + 1) * 4096 + grow];  // early issue
    float hv[16];
    pollN<16>(hg + ((size_t)((t + 1) & 1)) * 1024 + 16 * lane, (unsigned)t, hv);
    *(f4v*)&wreg[0]  = f4v{hv[0],  hv[1],  hv[2],  hv[3]};
    *(f4v*)&wreg[4]  = f4v{hv[4],  hv[5],  hv[6],  hv[7]};
    *(f4v*)&wreg[8]  = f4v{hv[8],  hv[9],  hv[10], hv[11]};
    *(f4v*)&wreg[12] = f4v{hv[12], hv[13], hv[14], hv[15]};
    float a0 = 0, a1 = 0, a2 = 0, a3 = 0;
#pragma unroll
    for (int j = 0; j < 64; ++j) {
      f4v h4 = *(const f4v*)&qreg[4 * j];          // 4 addrs/wave, conflict-free
      a0 = fmaf(wh4[j][0], h4[0], a0);
      a1 = fmaf(wh4[j][1], h4[1], a1);
      a2 = fmaf(wh4[j][2], h4[2], a2);
      a3 = fmaf(wh4[j][3], h4[3], a3);
    }
    float z = (a0 + a1) + (a2 + a3);
    z += __shfl_xor(z, 16);
    z += __shfl_xor(z, 32);                        // q-reduce
    z += xwv;                                      // own row's xw (consistent per (u,g))
    float zi  = __shfl(z, u);
    float zf  = __shfl(z, 4 + u);
    float zg2 = __shfl(z, 8 + u);
    float zo  = __shfl(z, 12 + u);
    if (lane < 4) {
      float cn = sigm(zf) * cst + sigm(zi) * tanh_f(zg2);
      float hn = sigm(zo) * tanh_f(cn);
      cst = cn;
      int hidx = 4 * gw + lane;
      store_tagged(&hg[((size_t)(t & 1)) * 1024 + hidx], hn, (unsigned)(t + 1));
      unsigned short hb = f2bf(hn);
      hhi[(size_t)t * 1024 + hidx] = hb;
      hlo[(size_t)t * 1024 + hidx] = f2bf(hn - bf2f(hb));
    }
    xwv = xwn;
  }
}

// ============================================================================
// lstm3: H=256. 4 WGs x 256 thr = 16 waves; wave owns 16 units;
// lane = full gate row (256 f32 in regs). Poll 4 tagged h per lane.
// ============================================================================
__global__ __launch_bounds__(256, 1) void lstm3_kernel(
    const float* __restrict__ Whh,   // [1024,256]
    const float* __restrict__ xw,    // [2048,1024] bias pre-folded
    unsigned long long* __restrict__ hg,   // [2][256] tagged
    float* __restrict__ hout)        // [2048,256]
{
  const int widx = threadIdx.x >> 6, lane = threadIdx.x & 63;
  const int gw = blockIdx.x * 4 + widx;          // 0..15
  const int u16 = lane & 15, g = lane >> 4;
  const int unit = 16 * gw + u16;
  const int grow = g * 256 + unit;

  f4v wh4[64];
  const f4v* wsrc = (const f4v*)(Whh + (size_t)grow * 256);
#pragma unroll
  for (int j = 0; j < 64; ++j) wh4[j] = wsrc[j];

  __shared__ __align__(16) float hws[4 * 256];
  float* const reg0 = &hws[widx * 256];

  float cst = 0.0f;
  float xwv = xw[grow];

  for (int t = 0; t < T_STEPS; ++t) {
    float xwn = 0.0f;
    if (t + 1 < T_STEPS) xwn = xw[(size_t)(t + 1) * 1024 + grow];
    float hv[4];
    pollN<4>(hg + ((size_t)((t + 1) & 1)) * 256 + 4 * lane, (unsigned)t, hv);
    *(f4v*)&reg0[4 * lane] = f4v{hv[0], hv[1], hv[2], hv[3]};
    float a0 = 0, a1 = 0, a2 = 0, a3 = 0;
#pragma unroll
    for (int j = 0; j < 64; ++j) {
      f4v h4 = *(const f4v*)&reg0[4 * j];
      a0 = fmaf(wh4[j][0], h4[0], a0);
      a1 = fmaf(wh4[j][1], h4[1], a1);
      a2 = fmaf(wh4[j][2], h4[2], a2);
      a3 = fmaf(wh4[j][3], h4[3], a3);
    }
    float z = (a0 + a1) + (a2 + a3) + xwv;
    float zi = __shfl(z, u16);
    float zf = __shfl(z, 16 + u16);
    float zg = __shfl(z, 32 + u16);
    float zo = __shfl(z, 48 + u16);
    if (lane < 16) {
      float cn = sigm(zf) * cst + sigm(zi) * tanh_f(zg);
      float hn = sigm(zo) * tanh_f(cn);
      cst = cn;
      int us = 16 * gw + lane;
      store_tagged(&hg[((size_t)(t & 1)) * 256 + us], hn, (unsigned)(t + 1));
      hout[(size_t)t * 256 + us] = hn;
    }
    xwv = xwn;
  }
}

// ============================================================================
// split fp32 -> (hi, lo) bf16
// ============================================================================
__global__ void split_kernel(const float* __restrict__ src,
                             unsigned short* __restrict__ hi,
                             unsigned short* __restrict__ lo, int n) {
  int i = blockIdx.x * 256 + threadIdx.x;
  if (i < n) {
    float v = src[i];
    unsigned short hb = f2bf(v);
    hi[i] = hb;
    lo[i] = f2bf(v - bf2f(hb));
  }
}

// ============================================================================
// Split-bf16 GEMM: C[M,N] = A[M,K] * Bt[N,K]^T + (b1+b2)[N], fp32 out.
// 128x128 tile, BK=32, 4 waves, 3 MFMAs per fragment (hi*hi, hi*lo, lo*hi).
// ============================================================================
__global__ __launch_bounds__(256) void gemm_split_kernel(
    const unsigned short* __restrict__ Ah, const unsigned short* __restrict__ Al,
    const unsigned short* __restrict__ Bh, const unsigned short* __restrict__ Bl,
    const float* __restrict__ b1, const float* __restrict__ b2,
    float* __restrict__ C, int M, int N, int K)
{
  __shared__ __align__(16) unsigned short lds[16384];
  const int mt = M >> 7;
  const int tm = blockIdx.x % mt, tn = blockIdx.x / mt;
  const size_t m0 = (size_t)tm * 128, n0 = (size_t)tn * 128;
  const int tid = threadIdx.x, lane = tid & 63, w = tid >> 6;
  const int wr = w >> 1, wc = w & 1;
  const int srow = tid >> 2, sc8 = (tid & 3) * 8;

  const unsigned short* pAh = Ah + m0 * K;
  const unsigned short* pAl = Al + m0 * K;
  const unsigned short* pBh = Bh + n0 * K;
  const unsigned short* pBl = Bl + n0 * K;

  f4v zero4 = {0.0f, 0.0f, 0.0f, 0.0f};
  f4v acc[4][4];
#pragma unroll
  for (int i = 0; i < 4; ++i)
#pragma unroll
    for (int j = 0; j < 4; ++j) acc[i][j] = zero4;

  u16x8 s0, s1, s2, s3, s4, s5, s6, s7;
#define LOADK(k0)                                                          \
  s0 = *(const u16x8*)(pAh + (size_t)srow * K + (k0) + sc8);               \
  s1 = *(const u16x8*)(pAh + (size_t)(srow + 64) * K + (k0) + sc8);        \
  s2 = *(const u16x8*)(pAl + (size_t)srow * K + (k0) + sc8);               \
  s3 = *(const u16x8*)(pAl + (size_t)(srow + 64) * K + (k0) + sc8);        \
  s4 = *(const u16x8*)(pBh + (size_t)srow * K + (k0) + sc8);               \
  s5 = *(const u16x8*)(pBh + (size_t)(srow + 64) * K + (k0) + sc8);        \
  s6 = *(const u16x8*)(pBl + (size_t)srow * K + (k0) + sc8);               \
  s7 = *(const u16x8*)(pBl + (size_t)(srow + 64) * K + (k0) + sc8);

  LOADK(0);
  const int fr = lane & 15, fko = (lane >> 4) * 8;
  for (int k0 = 0; k0 < K; k0 += 32) {
    *(u16x8*)&lds[0     +  srow       * 32 + sc8] = s0;
    *(u16x8*)&lds[0     + (srow + 64) * 32 + sc8] = s1;
    *(u16x8*)&lds[4096  +  srow       * 32 + sc8] = s2;
    *(u16x8*)&lds[4096  + (srow + 64) * 32 + sc8] = s3;
    *(u16x8*)&lds[8192  +  srow       * 32 + sc8] = s4;
    *(u16x8*)&lds[8192  + (srow + 64) * 32 + sc8] = s5;
    *(u16x8*)&lds[12288 +  srow       * 32 + sc8] = s6;
    *(u16x8*)&lds[12288 + (srow + 64) * 32 + sc8] = s7;
    __syncthreads();
    if (k0 + 32 < K) { LOADK(k0 + 32); }
    s8v afh[4], afl[4], bfh[4], bfl[4];
#pragma unroll
    for (int i = 0; i < 4; ++i) {
      int ar = (64 * wr + 16 * i + fr) * 32 + fko;
      int br = (64 * wc + 16 * i + fr) * 32 + fko;
      afh[i] = *(const s8v*)&lds[0 + ar];
      afl[i] = *(const s8v*)&lds[4096 + ar];
      bfh[i] = *(const s8v*)&lds[8192 + br];
      bfl[i] = *(const s8v*)&lds[12288 + br];
    }
#pragma unroll
    for (int mi = 0; mi < 4; ++mi)
#pragma unroll
      for (int ni = 0; ni < 4; ++ni) {
        acc[mi][ni] = __builtin_amdgcn_mfma_f32_16x16x32_bf16(afh[mi], bfh[ni], acc[mi][ni], 0, 0, 0);
        acc[mi][ni] = __builtin_amdgcn_mfma_f32_16x16x32_bf16(afh[mi], bfl[ni], acc[mi][ni], 0, 0, 0);
        acc[mi][ni] = __builtin_amdgcn_mfma_f32_16x16x32_bf16(afl[mi], bfh[ni], acc[mi][ni], 0, 0, 0);
      }
    __syncthreads();
  }
#undef LOADK
  const int er = (lane >> 4) * 4, ec = lane & 15;
#pragma unroll
  for (int ni = 0; ni < 4; ++ni) {
    size_t col = n0 + 64 * wc + 16 * ni + ec;
    float bv = b1[col] + b2[col];
#pragma unroll
    for (int mi = 0; mi < 4; ++mi) {
      size_t row = m0 + 64 * wr + 16 * mi + er;
#pragma unroll
      for (int rr = 0; rr < 4; ++rr)
        C[(row + rr) * N + col] = acc[mi][ni][rr] + bv;
    }
  }
}

// ============================================================================
// FC: out[t,m] = h3[t,:] . Wfc[m,:] + bfc[m]
// ============================================================================
__global__ void fc_kernel(const float* __restrict__ h3, const float* __restrict__ Wfc,
                          const float* __restrict__ bfc, float* __restrict__ out) {
  int t = blockIdx.x, m = threadIdx.x;
  if (m < 21) {
    const float* hp = h3 + (size_t)t * 256;
    const float* wp = Wfc + m * 256;
    float a = 0.0f;
#pragma unroll 8
    for (int j = 0; j < 256; ++j) a = fmaf(wp[j], hp[j], a);
    out[t * 21 + m] = a + bfc[m];
  }
}

// ============================================================================
// launch
// ============================================================================
extern "C" void kernel_launch(void* const* d_in, const int* in_sizes, int n_in,
                              void* d_out, int out_size, void* d_ws, size_t ws_size,
                              hipStream_t stream) {
  const float* x    = (const float*)d_in[0];
  const float* Wih1 = (const float*)d_in[1];
  const float* Whh1 = (const float*)d_in[2];
  const float* bih1 = (const float*)d_in[3];
  const float* bhh1 = (const float*)d_in[4];
  const float* Wih2 = (const float*)d_in[5];
  const float* Whh2 = (const float*)d_in[6];
  const float* bih2 = (const float*)d_in[7];
  const float* bhh2 = (const float*)d_in[8];
  const float* Wih3 = (const float*)d_in[9];
  const float* Whh3 = (const float*)d_in[10];
  const float* bih3 = (const float*)d_in[11];
  const float* bhh3 = (const float*)d_in[12];
  const float* Wfc  = (const float*)d_in[13];
  const float* bfc  = (const float*)d_in[14];
  float* out = (float*)d_out;

  const size_t WS_NEEDED = 186753024;
  if (ws_size < WS_NEEDED) return;
  char* ws = (char*)d_ws;
  unsigned long long* hg1 = (unsigned long long*)(ws + 0);       // 2*5376*8 = 86016
  unsigned long long* hg2 = (unsigned long long*)(ws + 86016);   // 2*1024*8 = 16384
  unsigned long long* hg3 = (unsigned long long*)(ws + 102400);  // 2*256*8  = 4096
  unsigned short* wih2h = (unsigned short*)(ws + 106496);
  unsigned short* wih2l = (unsigned short*)(ws + 44146688);
  unsigned short* wih3h = (unsigned short*)(ws + 88186880);
  unsigned short* wih3l = (unsigned short*)(ws + 90284032);
  unsigned short* h1h   = (unsigned short*)(ws + 92381184);
  unsigned short* h1l   = (unsigned short*)(ws + 114401280);
  unsigned short* h2h   = (unsigned short*)(ws + 136421376);
  unsigned short* h2l   = (unsigned short*)(ws + 140615680);
  float* xw2 = (float*)(ws + 144809984);   // [2048,4096]
  float* xw3 = (float*)(ws + 178364416);   // [2048,1024]
  float* h3  = (float*)(ws + 106496);      // [2048,256] — aliases wih2h (GEMM2 done)

  hipMemsetAsync(ws, 0, 106496, stream);   // zero all tag buffers every call

  const int nW2 = 4096 * 5376;
  split_kernel<<<(nW2 + 255) / 256, 256, 0, stream>>>(Wih2, wih2h, wih2l, nW2);
  const int nW3 = 1024 * 1024;
  split_kernel<<<(nW3 + 255) / 256, 256, 0, stream>>>(Wih3, wih3h, wih3l, nW3);

  lstm1_kernel<<<84, 256, 0, stream>>>(x, Wih1, Whh1, bih1, bhh1, hg1, h1h, h1l);

  gemm_split_kernel<<<(2048 / 128) * (4096 / 128), 256, 0, stream>>>(
      h1h, h1l, wih2h, wih2l, bih2, bhh2, xw2, 2048, 4096, 5376);

  lstm2_kernel<<<64, 256, 0, stream>>>(Whh2, xw2, hg2, h2h, h2l);

  gemm_split_kernel<<<(2048 / 128) * (1024 / 128), 256, 0, stream>>>(
      h2h, h2l, wih3h, wih3l, bih3, bhh3, xw3, 2048, 1024, 1024);

  lstm3_kernel<<<4, 256, 0, stream>>>(Whh3, xw3, hg3, h3);

  fc_kernel<<<2048, 64, 0, stream>>>(h3, Wfc, bfc, out);
}

// Round 4
// 21957.227 us; speedup vs baseline: 1.5029x; 1.5029x over previous
//
#include <hip/hip_runtime.h>

// ============================================================================
// 3-layer stacked LSTM (T=2048), MI355X — round 4.
// Wave-autonomous recurrence (no __syncthreads in step loops) with:
//  - coalesced strided tag-polls (lane l polls h[64k+l]; each line fetched 1x)
//  - conflict-free wave-private LDS staging
//  - recurrent weights FORCED into VGPRs via named f4v variables
// Tagged-data handshake: h stored as (f32,tag) u64 AGENT atomics, dbl-buffered.
// ============================================================================

#define T_STEPS 2048

using f4v   = __attribute__((ext_vector_type(4))) float;
using s8v   = __attribute__((ext_vector_type(8))) short;
using u16x8 = __attribute__((ext_vector_type(8))) unsigned short;

union HU { unsigned long long u; unsigned v[2]; float f[2]; };

__device__ __forceinline__ unsigned short f2bf(float v) {
  unsigned u = __float_as_uint(v);
  u = (u + 0x7FFFu + ((u >> 16) & 1u)) >> 16;   // RNE
  return (unsigned short)u;
}
__device__ __forceinline__ float bf2f(unsigned short b) {
  return __uint_as_float(((unsigned)b) << 16);
}
__device__ __forceinline__ float sigm(float x) { return 1.0f / (1.0f + __expf(-x)); }
__device__ __forceinline__ float tanh_f(float x) {
  float ax = fabsf(x);
  float e = __expf(-2.0f * ax);
  float t = (1.0f - e) / (1.0f + e);
  return copysignf(t, x);
}
__device__ __forceinline__ unsigned long long ld_agent(const unsigned long long* p) {
  return __hip_atomic_load(p, __ATOMIC_RELAXED, __HIP_MEMORY_SCOPE_AGENT);
}
__device__ __forceinline__ void st_agent(unsigned long long* p, unsigned long long v) {
  __hip_atomic_store(p, v, __ATOMIC_RELAXED, __HIP_MEMORY_SCOPE_AGENT);
}
__device__ __forceinline__ void store_tagged(unsigned long long* p, float v, unsigned tag) {
  HU c; c.f[0] = v; c.v[1] = tag;
  st_agent(p, c.u);
}

// Poll N u64 at p[64k+lane] (coalesced: each instr = 512 contiguous bytes).
template <int N_>
__device__ __forceinline__ void poll_strided(const unsigned long long* p, int lane,
                                             unsigned tgt, float* out) {
  HU c[N_];
#pragma unroll
  for (int k = 0; k < N_; ++k) c[k].u = ld_agent(p + 64 * k + lane);
  unsigned n = 0;
  for (;;) {
    bool ok = true;
#pragma unroll
    for (int k = 0; k < N_; ++k) ok &= (c[k].v[1] >= tgt);
    if (ok || ++n > (1u << 20)) break;          // parachute
#pragma unroll
    for (int k = 0; k < N_; ++k) c[k].u = ld_agent(p + 64 * k + lane);
  }
#pragma unroll
  for (int k = 0; k < N_; ++k) out[k] = c[k].f[0];
}

// ---- repetition lists for named-register weight variables -----------------
#define L8(M) M(0) M(1) M(2) M(3) M(4) M(5) M(6) M(7)
#define L32(M) L8(M) M(8) M(9) M(10) M(11) M(12) M(13) M(14) M(15) M(16) M(17) \
  M(18) M(19) M(20) M(21) M(22) M(23) M(24) M(25) M(26) M(27) M(28) M(29) M(30) M(31)
#define L64(M) L32(M) M(32) M(33) M(34) M(35) M(36) M(37) M(38) M(39) M(40) M(41) \
  M(42) M(43) M(44) M(45) M(46) M(47) M(48) M(49) M(50) M(51) M(52) M(53) M(54) \
  M(55) M(56) M(57) M(58) M(59) M(60) M(61) M(62) M(63)

// ============================================================================
// lstm1: 21 channels x H=256, shared weights. 168 WGs (8/channel) x 4 waves.
// Wave owns 8 units (32 gate rows); lane = (half hh=lane>>5, row r32=lane&31),
// half-row = 128 Whh + 32 Wih f32 in named VGPRs. Fused input projection.
// ============================================================================
__global__ __launch_bounds__(256, 1) void lstm1_kernel(
    const float* __restrict__ x,     // [2048,64,21]
    const float* __restrict__ Wih,   // [1024,64]
    const float* __restrict__ Whh,   // [1024,256]
    const float* __restrict__ bih, const float* __restrict__ bhh,
    unsigned long long* __restrict__ hg,   // [2][21*256] tagged
    unsigned short* __restrict__ h1hi, unsigned short* __restrict__ h1lo) // [2048,5376]
{
  const int c = blockIdx.x >> 3;
  const int sub = blockIdx.x & 7;
  const int widx = threadIdx.x >> 6, lane = threadIdx.x & 63;
  const int gwv = sub * 4 + widx;              // 0..31
  const int hh = lane >> 5, r32 = lane & 31;
  const int u = r32 & 7, g = r32 >> 3;
  const int grow = g * 256 + gwv * 8 + u;

  const f4v* wsrc = (const f4v*)(Whh + (size_t)grow * 256 + hh * 128);
  const f4v* xsrc = (const f4v*)(Wih + (size_t)grow * 64 + hh * 32);
#define DH(i) f4v m##i = wsrc[i];
#define DX(i) f4v n##i = xsrc[i];
  L32(DH)
  L8(DX)
#undef DH
#undef DX
  const float bias = bih[grow] + bhh[grow];

  __shared__ __align__(16) float sh1[4][344];  // per wave: h 2x132 + x 2x36
  float* const hls = &sh1[widx][0];
  float* const xls = &sh1[widx][264];
  const float* const hq = hls + hh * 132;
  const float* const xq = xls + hh * 36;

  float cst = 0.0f;
  float xpre = x[(size_t)lane * 21 + c];

  for (int t = 0; t < T_STEPS; ++t) {
    xls[(lane >> 5) * 36 + (lane & 31)] = xpre;
    if (t + 1 < T_STEPS) xpre = x[(size_t)(t + 1) * 1344 + lane * 21 + c];
    float hv[4];
    poll_strided<4>(hg + ((size_t)((t + 1) & 1)) * 5376 + c * 256, lane,
                    (unsigned)t, hv);
    hls[lane]       = hv[0];
    hls[64 + lane]  = hv[1];
    hls[132 + lane] = hv[2];
    hls[196 + lane] = hv[3];
    float a0 = 0, a1 = 0, a2 = 0, a3 = 0;
#define FH(i) { f4v h4 = *(const f4v*)&hq[4 * i]; \
  a0 = fmaf(m##i[0], h4[0], a0); a1 = fmaf(m##i[1], h4[1], a1); \
  a2 = fmaf(m##i[2], h4[2], a2); a3 = fmaf(m##i[3], h4[3], a3); }
#define FX(i) { f4v x4 = *(const f4v*)&xq[4 * i]; \
  a0 = fmaf(n##i[0], x4[0], a0); a1 = fmaf(n##i[1], x4[1], a1); \
  a2 = fmaf(n##i[2], x4[2], a2); a3 = fmaf(n##i[3], x4[3], a3); }
    L32(FH)
    L8(FX)
#undef FH
#undef FX
    float z = (a0 + a1) + (a2 + a3);
    z += __shfl_xor(z, 32);                    // combine halves
    z += bias;
    float zi = __shfl(z, u);
    float zf = __shfl(z, 8 + u);
    float zg = __shfl(z, 16 + u);
    float zo = __shfl(z, 24 + u);
    if (lane < 8) {
      float cn = sigm(zf) * cst + sigm(zi) * tanh_f(zg);
      float hn = sigm(zo) * tanh_f(cn);
      cst = cn;
      int hidx = c * 256 + gwv * 8 + lane;
      store_tagged(&hg[((size_t)(t & 1)) * 5376 + hidx], hn, (unsigned)(t + 1));
      unsigned short hb = f2bf(hn);
      h1hi[(size_t)t * 5376 + hidx] = hb;
      h1lo[(size_t)t * 5376 + hidx] = f2bf(hn - bf2f(hb));
    }
  }
}

// ============================================================================
// lstm2: H2=1024. 64 WGs x 4 waves = 256 waves; wave owns 4 units (16 rows).
// lane = (q=lane>>4 quarter, r4=lane&15 row: u=r4&3, g=r4>>2); quarter-row =
// 256 f32 in named VGPRs. Poll strided, stage to skewed wave-private LDS,
// broadcast FMA, shfl_xor(16,32) reduce, shfl gather, 4 lanes gates+store.
// ============================================================================
__global__ __launch_bounds__(256, 1) void lstm2_kernel(
    const float* __restrict__ Whh,   // [4096,1024]
    const float* __restrict__ xw,    // [2048,4096] bias pre-folded
    unsigned long long* __restrict__ hg,   // [2][1024] tagged
    unsigned short* __restrict__ hhi, unsigned short* __restrict__ hlo)  // [2048,1024]
{
  const int widx = threadIdx.x >> 6, lane = threadIdx.x & 63;
  const int gw = blockIdx.x * 4 + widx;        // 0..255
  const int q = lane >> 4, r4 = lane & 15;
  const int u = r4 & 3, g = r4 >> 2;
  const int grow = g * 1024 + gw * 4 + u;

  const f4v* wsrc = (const f4v*)(Whh + (size_t)grow * 1024 + q * 256);
#define DW(i) f4v w##i = wsrc[i];
  L64(DW)
#undef DW

  __shared__ __align__(16) float sh2[4][1056]; // 4 quarters x 260 (skew 4)
  float* const hls = &sh2[widx][0];
  const float* const qreg = hls + q * 260;

  float cst = 0.0f;
  float xwv = xw[grow];

  for (int t = 0; t < T_STEPS; ++t) {
    float xwn = 0.0f;
    if (t + 1 < T_STEPS) xwn = xw[(size_t)(t + 1) * 4096 + grow];  // early issue
    float hv[16];
    poll_strided<16>(hg + ((size_t)((t + 1) & 1)) * 1024, lane, (unsigned)t, hv);
#pragma unroll
    for (int k = 0; k < 16; ++k)
      hls[(k >> 2) * 260 + 64 * (k & 3) + lane] = hv[k];
    float a0 = 0, a1 = 0, a2 = 0, a3 = 0;
#define FW(i) { f4v h4 = *(const f4v*)&qreg[4 * i]; \
  a0 = fmaf(w##i[0], h4[0], a0); a1 = fmaf(w##i[1], h4[1], a1); \
  a2 = fmaf(w##i[2], h4[2], a2); a3 = fmaf(w##i[3], h4[3], a3); }
    L64(FW)
#undef FW
    float z = (a0 + a1) + (a2 + a3);
    z += __shfl_xor(z, 16);
    z += __shfl_xor(z, 32);                    // quarters summed
    z += xwv;
    float zi  = __shfl(z, u);
    float zf  = __shfl(z, 4 + u);
    float zg2 = __shfl(z, 8 + u);
    float zo  = __shfl(z, 12 + u);
    if (lane < 4) {
      float cn = sigm(zf) * cst + sigm(zi) * tanh_f(zg2);
      float hn = sigm(zo) * tanh_f(cn);
      cst = cn;
      int hidx = gw * 4 + lane;
      store_tagged(&hg[((size_t)(t & 1)) * 1024 + hidx], hn, (unsigned)(t + 1));
      unsigned short hb = f2bf(hn);
      hhi[(size_t)t * 1024 + hidx] = hb;
      hlo[(size_t)t * 1024 + hidx] = f2bf(hn - bf2f(hb));
    }
    xwv = xwn;
  }
}

// ============================================================================
// lstm3: H=256. 4 WGs x 4 waves = 16 waves; wave owns 16 units; lane = full
// gate row (256 f32 in named VGPRs). Strided poll, linear LDS, broadcast FMA.
// ============================================================================
__global__ __launch_bounds__(256, 1) void lstm3_kernel(
    const float* __restrict__ Whh,   // [1024,256]
    const float* __restrict__ xw,    // [2048,1024] bias pre-folded
    unsigned long long* __restrict__ hg,   // [2][256] tagged
    float* __restrict__ hout)        // [2048,256]
{
  const int widx = threadIdx.x >> 6, lane = threadIdx.x & 63;
  const int gw = blockIdx.x * 4 + widx;        // 0..15
  const int u16 = lane & 15, g = lane >> 4;
  const int grow = g * 256 + gw * 16 + u16;

  const f4v* wsrc = (const f4v*)(Whh + (size_t)grow * 256);
#define DW(i) f4v w##i = wsrc[i];
  L64(DW)
#undef DW

  __shared__ __align__(16) float sh3[4][256];
  float* const hls = &sh3[widx][0];
  const float* const qreg = hls;               // all-lane broadcast reads

  float cst = 0.0f;
  float xwv = xw[grow];

  for (int t = 0; t < T_STEPS; ++t) {
    float xwn = 0.0f;
    if (t + 1 < T_STEPS) xwn = xw[(size_t)(t + 1) * 1024 + grow];
    float hv[4];
    poll_strided<4>(hg + ((size_t)((t + 1) & 1)) * 256, lane, (unsigned)t, hv);
    hls[lane]       = hv[0];
    hls[64 + lane]  = hv[1];
    hls[128 + lane] = hv[2];
    hls[192 + lane] = hv[3];
    float a0 = 0, a1 = 0, a2 = 0, a3 = 0;
#define FW(i) { f4v h4 = *(const f4v*)&qreg[4 * i]; \
  a0 = fmaf(w##i[0], h4[0], a0); a1 = fmaf(w##i[1], h4[1], a1); \
  a2 = fmaf(w##i[2], h4[2], a2); a3 = fmaf(w##i[3], h4[3], a3); }
    L64(FW)
#undef FW
    float z = (a0 + a1) + (a2 + a3) + xwv;
    float zi = __shfl(z, u16);
    float zf = __shfl(z, 16 + u16);
    float zg = __shfl(z, 32 + u16);
    float zo = __shfl(z, 48 + u16);
    if (lane < 16) {
      float cn = sigm(zf) * cst + sigm(zi) * tanh_f(zg);
      float hn = sigm(zo) * tanh_f(cn);
      cst = cn;
      int us = gw * 16 + lane;
      store_tagged(&hg[((size_t)(t & 1)) * 256 + us], hn, (unsigned)(t + 1));
      hout[(size_t)t * 256 + us] = hn;
    }
    xwv = xwn;
  }
}

// ============================================================================
// split fp32 -> (hi, lo) bf16
// ============================================================================
__global__ void split_kernel(const float* __restrict__ src,
                             unsigned short* __restrict__ hi,
                             unsigned short* __restrict__ lo, int n) {
  int i = blockIdx.x * 256 + threadIdx.x;
  if (i < n) {
    float v = src[i];
    unsigned short hb = f2bf(v);
    hi[i] = hb;
    lo[i] = f2bf(v - bf2f(hb));
  }
}

// ============================================================================
// Split-bf16 GEMM: C[M,N] = A[M,K] * Bt[N,K]^T + (b1+b2)[N], fp32 out.
// 128x128 tile, BK=32, 4 waves, 3 MFMAs per fragment (hi*hi, hi*lo, lo*hi).
// ============================================================================
__global__ __launch_bounds__(256) void gemm_split_kernel(
    const unsigned short* __restrict__ Ah, const unsigned short* __restrict__ Al,
    const unsigned short* __restrict__ Bh, const unsigned short* __restrict__ Bl,
    const float* __restrict__ b1, const float* __restrict__ b2,
    float* __restrict__ C, int M, int N, int K)
{
  __shared__ __align__(16) unsigned short lds[16384];
  const int mt = M >> 7;
  const int tm = blockIdx.x % mt, tn = blockIdx.x / mt;
  const size_t m0 = (size_t)tm * 128, n0 = (size_t)tn * 128;
  const int tid = threadIdx.x, lane = tid & 63, w = tid >> 6;
  const int wr = w >> 1, wc = w & 1;
  const int srow = tid >> 2, sc8 = (tid & 3) * 8;

  const unsigned short* pAh = Ah + m0 * K;
  const unsigned short* pAl = Al + m0 * K;
  const unsigned short* pBh = Bh + n0 * K;
  const unsigned short* pBl = Bl + n0 * K;

  f4v zero4 = {0.0f, 0.0f, 0.0f, 0.0f};
  f4v acc[4][4];
#pragma unroll
  for (int i = 0; i < 4; ++i)
#pragma unroll
    for (int j = 0; j < 4; ++j) acc[i][j] = zero4;

  u16x8 s0, s1, s2, s3, s4, s5, s6, s7;
#define LOADK(k0)                                                          \
  s0 = *(const u16x8*)(pAh + (size_t)srow * K + (k0) + sc8);               \
  s1 = *(const u16x8*)(pAh + (size_t)(srow + 64) * K + (k0) + sc8);        \
  s2 = *(const u16x8*)(pAl + (size_t)srow * K + (k0) + sc8);               \
  s3 = *(const u16x8*)(pAl + (size_t)(srow + 64) * K + (k0) + sc8);        \
  s4 = *(const u16x8*)(pBh + (size_t)srow * K + (k0) + sc8);               \
  s5 = *(const u16x8*)(pBh + (size_t)(srow + 64) * K + (k0) + sc8);        \
  s6 = *(const u16x8*)(pBl + (size_t)srow * K + (k0) + sc8);               \
  s7 = *(const u16x8*)(pBl + (size_t)(srow + 64) * K + (k0) + sc8);

  LOADK(0);
  const int fr = lane & 15, fko = (lane >> 4) * 8;
  for (int k0 = 0; k0 < K; k0 += 32) {
    *(u16x8*)&lds[0     +  srow       * 32 + sc8] = s0;
    *(u16x8*)&lds[0     + (srow + 64) * 32 + sc8] = s1;
    *(u16x8*)&lds[4096  +  srow       * 32 + sc8] = s2;
    *(u16x8*)&lds[4096  + (srow + 64) * 32 + sc8] = s3;
    *(u16x8*)&lds[8192  +  srow       * 32 + sc8] = s4;
    *(u16x8*)&lds[8192  + (srow + 64) * 32 + sc8] = s5;
    *(u16x8*)&lds[12288 +  srow       * 32 + sc8] = s6;
    *(u16x8*)&lds[12288 + (srow + 64) * 32 + sc8] = s7;
    __syncthreads();
    if (k0 + 32 < K) { LOADK(k0 + 32); }
    s8v afh[4], afl[4], bfh[4], bfl[4];
#pragma unroll
    for (int i = 0; i < 4; ++i) {
      int ar = (64 * wr + 16 * i + fr) * 32 + fko;
      int br = (64 * wc + 16 * i + fr) * 32 + fko;
      afh[i] = *(const s8v*)&lds[0 + ar];
      afl[i] = *(const s8v*)&lds[4096 + ar];
      bfh[i] = *(const s8v*)&lds[8192 + br];
      bfl[i] = *(const s8v*)&lds[12288 + br];
    }
#pragma unroll
    for (int mi = 0; mi < 4; ++mi)
#pragma unroll
      for (int ni = 0; ni < 4; ++ni) {
        acc[mi][ni] = __builtin_amdgcn_mfma_f32_16x16x32_bf16(afh[mi], bfh[ni], acc[mi][ni], 0, 0, 0);
        acc[mi][ni] = __builtin_amdgcn_mfma_f32_16x16x32_bf16(afh[mi], bfl[ni], acc[mi][ni], 0, 0, 0);
        acc[mi][ni] = __builtin_amdgcn_mfma_f32_16x16x32_bf16(afl[mi], bfh[ni], acc[mi][ni], 0, 0, 0);
      }
    __syncthreads();
  }
#undef LOADK
  const int er = (lane >> 4) * 4, ec = lane & 15;
#pragma unroll
  for (int ni = 0; ni < 4; ++ni) {
    size_t col = n0 + 64 * wc + 16 * ni + ec;
    float bv = b1[col] + b2[col];
#pragma unroll
    for (int mi = 0; mi < 4; ++mi) {
      size_t row = m0 + 64 * wr + 16 * mi + er;
#pragma unroll
      for (int rr = 0; rr < 4; ++rr)
        C[(row + rr) * N + col] = acc[mi][ni][rr] + bv;
    }
  }
}

// ============================================================================
// FC: out[t,m] = h3[t,:] . Wfc[m,:] + bfc[m]
// ============================================================================
__global__ void fc_kernel(const float* __restrict__ h3, const float* __restrict__ Wfc,
                          const float* __restrict__ bfc, float* __restrict__ out) {
  int t = blockIdx.x, m = threadIdx.x;
  if (m < 21) {
    const float* hp = h3 + (size_t)t * 256;
    const float* wp = Wfc + m * 256;
    float a = 0.0f;
#pragma unroll 8
    for (int j = 0; j < 256; ++j) a = fmaf(wp[j], hp[j], a);
    out[t * 21 + m] = a + bfc[m];
  }
}

// ============================================================================
// launch
// ============================================================================
extern "C" void kernel_launch(void* const* d_in, const int* in_sizes, int n_in,
                              void* d_out, int out_size, void* d_ws, size_t ws_size,
                              hipStream_t stream) {
  const float* x    = (const float*)d_in[0];
  const float* Wih1 = (const float*)d_in[1];
  const float* Whh1 = (const float*)d_in[2];
  const float* bih1 = (const float*)d_in[3];
  const float* bhh1 = (const float*)d_in[4];
  const float* Wih2 = (const float*)d_in[5];
  const float* Whh2 = (const float*)d_in[6];
  const float* bih2 = (const float*)d_in[7];
  const float* bhh2 = (const float*)d_in[8];
  const float* Wih3 = (const float*)d_in[9];
  const float* Whh3 = (const float*)d_in[10];
  const float* bih3 = (const float*)d_in[11];
  const float* bhh3 = (const float*)d_in[12];
  const float* Wfc  = (const float*)d_in[13];
  const float* bfc  = (const float*)d_in[14];
  float* out = (float*)d_out;

  const size_t WS_NEEDED = 186753024;
  if (ws_size < WS_NEEDED) return;
  char* ws = (char*)d_ws;
  unsigned long long* hg1 = (unsigned long long*)(ws + 0);       // 2*5376*8
  unsigned long long* hg2 = (unsigned long long*)(ws + 86016);   // 2*1024*8
  unsigned long long* hg3 = (unsigned long long*)(ws + 102400);  // 2*256*8
  unsigned short* wih2h = (unsigned short*)(ws + 106496);
  unsigned short* wih2l = (unsigned short*)(ws + 44146688);
  unsigned short* wih3h = (unsigned short*)(ws + 88186880);
  unsigned short* wih3l = (unsigned short*)(ws + 90284032);
  unsigned short* h1h   = (unsigned short*)(ws + 92381184);
  unsigned short* h1l   = (unsigned short*)(ws + 114401280);
  unsigned short* h2h   = (unsigned short*)(ws + 136421376);
  unsigned short* h2l   = (unsigned short*)(ws + 140615680);
  float* xw2 = (float*)(ws + 144809984);   // [2048,4096]
  float* xw3 = (float*)(ws + 178364416);   // [2048,1024]
  float* h3  = (float*)(ws + 106496);      // [2048,256] — aliases wih2h (GEMM2 done)

  hipMemsetAsync(ws, 0, 106496, stream);   // zero all tag buffers every call

  const int nW2 = 4096 * 5376;
  split_kernel<<<(nW2 + 255) / 256, 256, 0, stream>>>(Wih2, wih2h, wih2l, nW2);
  const int nW3 = 1024 * 1024;
  split_kernel<<<(nW3 + 255) / 256, 256, 0, stream>>>(Wih3, wih3h, wih3l, nW3);

  lstm1_kernel<<<168, 256, 0, stream>>>(x, Wih1, Whh1, bih1, bhh1, hg1, h1h, h1l);

  gemm_split_kernel<<<(2048 / 128) * (4096 / 128), 256, 0, stream>>>(
      h1h, h1l, wih2h, wih2l, bih2, bhh2, xw2, 2048, 4096, 5376);

  lstm2_kernel<<<64, 256, 0, stream>>>(Whh2, xw2, hg2, h2h, h2l);

  gemm_split_kernel<<<(2048 / 128) * (1024 / 128), 256, 0, stream>>>(
      h2h, h2l, wih3h, wih3l, bih3, bhh3, xw3, 2048, 1024, 1024);

  lstm3_kernel<<<4, 256, 0, stream>>>(Whh3, xw3, hg3, h3);

  fc_kernel<<<2048, 64, 0, stream>>>(h3, Wfc, bfc, out);
}

// Round 5
// 9879.739 us; speedup vs baseline: 3.3401x; 2.2224x over previous
//
#include <hip/hip_runtime.h>

// ============================================================================
// 3-layer stacked LSTM (T=2048), MI355X — round 5: fused pipelined mega-kernel.
// Roles by blockIdx (220 WGs, all co-resident; 1 WG/CU forced by VGPR use):
//   [0,84)   lstm1 : 21 ch x 4 WG, lane = full gate row (320 f32 wts in regs)
//   [84,148) lstm2 : 64 WG, wave owns 4 units, lane = quarter-row (256 f32)
//   [148,152)lstm3 : 4 WG, lane = full gate row (256 f32)
//   [152,206)gemm2 pool (54 WG): xw2 tiles, split-bf16 MFMA, packed-u32 A
//   [206,220)gemm3 pool (14 WG): xw3 tiles
// h history stored as packed (bf16hi|bf16lo) u32 agent atomics into full
// [2048]-row buffers pre-filled with 0xFFFFFFFF; consumers poll != SENT
// (single LLC round trip carries data+readiness). Bulk xw production gated by
// tile counters: producers vmcnt(0)-drain then ctr_add; consumers poll ctr.
// Biases are folded into the xw GEMMs (b1+b2); lstm1 adds its own bias.
// ============================================================================

#define T_STEPS 2048
#define SENT 0xFFFFFFFFu

using f4v   = __attribute__((ext_vector_type(4))) float;
using s8v   = __attribute__((ext_vector_type(8))) short;
using u16x8 = __attribute__((ext_vector_type(8))) unsigned short;
using u32x4 = __attribute__((ext_vector_type(4))) unsigned;

__device__ __forceinline__ unsigned short f2bf(float v) {
  unsigned u = __float_as_uint(v);
  u = (u + 0x7FFFu + ((u >> 16) & 1u)) >> 16;   // RNE
  return (unsigned short)u;
}
__device__ __forceinline__ float bf2f(unsigned short b) {
  return __uint_as_float(((unsigned)b) << 16);
}
__device__ __forceinline__ unsigned packhl(float v) {
  unsigned short hb = f2bf(v);
  unsigned short lb = f2bf(v - bf2f(hb));
  return (((unsigned)hb) << 16) | lb;
}
__device__ __forceinline__ float unpackhl(unsigned p) {
  return __uint_as_float(p & 0xFFFF0000u) + __uint_as_float(p << 16);
}
__device__ __forceinline__ float sigm(float x) { return 1.0f / (1.0f + __expf(-x)); }
__device__ __forceinline__ float tanh_f(float x) {
  float ax = fabsf(x);
  float e = __expf(-2.0f * ax);
  float t = (1.0f - e) / (1.0f + e);
  return copysignf(t, x);
}
__device__ __forceinline__ unsigned ld_agent32(const unsigned* p) {
  return __hip_atomic_load(p, __ATOMIC_RELAXED, __HIP_MEMORY_SCOPE_AGENT);
}
__device__ __forceinline__ void st_agent32(unsigned* p, unsigned v) {
  __hip_atomic_store(p, v, __ATOMIC_RELAXED, __HIP_MEMORY_SCOPE_AGENT);
}
__device__ __forceinline__ void ctr_add(unsigned* p) {
  __hip_atomic_fetch_add(p, 1u, __ATOMIC_RELAXED, __HIP_MEMORY_SCOPE_AGENT);
}
__device__ __forceinline__ void poll_ctr(const unsigned* p, unsigned tgt) {
  unsigned n = 0;
  while (ld_agent32(p) < tgt) {
    if (++n > (1u << 22)) break;               // parachute
    __builtin_amdgcn_s_sleep(4);
  }
}
template <int N_>
__device__ __forceinline__ void poll_sent(const unsigned* p, int lane, unsigned* c) {
#pragma unroll
  for (int k = 0; k < N_; ++k) c[k] = ld_agent32(p + 64 * k + lane);
  unsigned n = 0;
  for (;;) {
    bool ok = true;
#pragma unroll
    for (int k = 0; k < N_; ++k) ok &= (c[k] != SENT);
    if (ok || ++n > (1u << 20)) break;         // parachute
    __builtin_amdgcn_s_sleep(1);
#pragma unroll
    for (int k = 0; k < N_; ++k) c[k] = ld_agent32(p + 64 * k + lane);
  }
}
#define VMCNT0() asm volatile("s_waitcnt vmcnt(0)" ::: "memory")

#define L16(M) M(0) M(1) M(2) M(3) M(4) M(5) M(6) M(7) M(8) M(9) M(10) M(11) \
  M(12) M(13) M(14) M(15)
#define L64(M) L16(M) M(16) M(17) M(18) M(19) M(20) M(21) M(22) M(23) M(24) \
  M(25) M(26) M(27) M(28) M(29) M(30) M(31) M(32) M(33) M(34) M(35) M(36) \
  M(37) M(38) M(39) M(40) M(41) M(42) M(43) M(44) M(45) M(46) M(47) M(48) \
  M(49) M(50) M(51) M(52) M(53) M(54) M(55) M(56) M(57) M(58) M(59) M(60) \
  M(61) M(62) M(63)

// ---------------------------------------------------------------------------
// split-bf16 GEMM tile, A = packed (hi|lo) u32, C = A*B^T + (b1+b2), atomic C
// ---------------------------------------------------------------------------
__device__ __forceinline__ void unpack8(u32x4 a, u32x4 b, u16x8& hi, u16x8& lo) {
#pragma unroll
  for (int j = 0; j < 4; ++j) {
    hi[j]     = (unsigned short)(a[j] >> 16);
    lo[j]     = (unsigned short)(a[j] & 0xFFFFu);
    hi[4 + j] = (unsigned short)(b[j] >> 16);
    lo[4 + j] = (unsigned short)(b[j] & 0xFFFFu);
  }
}

__device__ void gemm_tile_packed(
    const unsigned* __restrict__ Ap, const unsigned short* __restrict__ Bh,
    const unsigned short* __restrict__ Bl, const float* __restrict__ b1,
    const float* __restrict__ b2, unsigned* __restrict__ C,
    int tm, int tn, int K, int N, char* smem)
{
  unsigned short* lds = (unsigned short*)smem;   // Ah|Al|Bh|Bl planes [128][32]
  const size_t m0 = (size_t)tm * 128, n0 = (size_t)tn * 128;
  const int tid = threadIdx.x, lane = tid & 63, w = tid >> 6;
  const int wr = w >> 1, wc = w & 1;
  const int srow = tid >> 2, sc8 = (tid & 3) * 8;

  const unsigned* pA = Ap + m0 * K;
  const unsigned short* pBh = Bh + n0 * K;
  const unsigned short* pBl = Bl + n0 * K;

  f4v acc[4][4];
#pragma unroll
  for (int i = 0; i < 4; ++i)
#pragma unroll
    for (int j = 0; j < 4; ++j) acc[i][j] = f4v{0.f, 0.f, 0.f, 0.f};

  u32x4 a00, a01, a10, a11;
  u16x8 s4, s5, s6, s7;
#define LOADK(k0)                                                           \
  a00 = *(const u32x4*)(pA + (size_t)srow * K + (k0) + sc8);                \
  a01 = *(const u32x4*)(pA + (size_t)srow * K + (k0) + sc8 + 4);            \
  a10 = *(const u32x4*)(pA + (size_t)(srow + 64) * K + (k0) + sc8);         \
  a11 = *(const u32x4*)(pA + (size_t)(srow + 64) * K + (k0) + sc8 + 4);     \
  s4 = *(const u16x8*)(pBh + (size_t)srow * K + (k0) + sc8);                \
  s5 = *(const u16x8*)(pBh + (size_t)(srow + 64) * K + (k0) + sc8);         \
  s6 = *(const u16x8*)(pBl + (size_t)srow * K + (k0) + sc8);                \
  s7 = *(const u16x8*)(pBl + (size_t)(srow + 64) * K + (k0) + sc8);

  LOADK(0);
  const int fr = lane & 15, fko = (lane >> 4) * 8;
  for (int k0 = 0; k0 < K; k0 += 32) {
    u16x8 h0, l0, h1, l1;
    unpack8(a00, a01, h0, l0);
    unpack8(a10, a11, h1, l1);
    *(u16x8*)&lds[0     +  srow       * 32 + sc8] = h0;
    *(u16x8*)&lds[0     + (srow + 64) * 32 + sc8] = h1;
    *(u16x8*)&lds[4096  +  srow       * 32 + sc8] = l0;
    *(u16x8*)&lds[4096  + (srow + 64) * 32 + sc8] = l1;
    *(u16x8*)&lds[8192  +  srow       * 32 + sc8] = s4;
    *(u16x8*)&lds[8192  + (srow + 64) * 32 + sc8] = s5;
    *(u16x8*)&lds[12288 +  srow       * 32 + sc8] = s6;
    *(u16x8*)&lds[12288 + (srow + 64) * 32 + sc8] = s7;
    __syncthreads();
    if (k0 + 32 < K) { LOADK(k0 + 32); }
    s8v afh[4], afl[4], bfh[4], bfl[4];
#pragma unroll
    for (int i = 0; i < 4; ++i) {
      int ar = (64 * wr + 16 * i + fr) * 32 + fko;
      int br = (64 * wc + 16 * i + fr) * 32 + fko;
      afh[i] = *(const s8v*)&lds[0 + ar];
      afl[i] = *(const s8v*)&lds[4096 + ar];
      bfh[i] = *(const s8v*)&lds[8192 + br];
      bfl[i] = *(const s8v*)&lds[12288 + br];
    }
#pragma unroll
    for (int mi = 0; mi < 4; ++mi)
#pragma unroll
      for (int ni = 0; ni < 4; ++ni) {
        acc[mi][ni] = __builtin_amdgcn_mfma_f32_16x16x32_bf16(afh[mi], bfh[ni], acc[mi][ni], 0, 0, 0);
        acc[mi][ni] = __builtin_amdgcn_mfma_f32_16x16x32_bf16(afh[mi], bfl[ni], acc[mi][ni], 0, 0, 0);
        acc[mi][ni] = __builtin_amdgcn_mfma_f32_16x16x32_bf16(afl[mi], bfh[ni], acc[mi][ni], 0, 0, 0);
      }
    __syncthreads();
  }
#undef LOADK
  const int er = (lane >> 4) * 4, ec = lane & 15;
#pragma unroll
  for (int ni = 0; ni < 4; ++ni) {
    size_t col = n0 + 64 * wc + 16 * ni + ec;
    float bv = b1[col] + b2[col];
#pragma unroll
    for (int mi = 0; mi < 4; ++mi) {
      size_t row = m0 + 64 * wr + 16 * mi + er;
#pragma unroll
      for (int rr = 0; rr < 4; ++rr)
        st_agent32(&C[(row + rr) * N + col], __float_as_uint(acc[mi][ni][rr] + bv));
    }
  }
}

// ---------------------------------------------------------------------------
// mega kernel
// ---------------------------------------------------------------------------
__global__ __launch_bounds__(256, 1) void mega_kernel(
    const float* __restrict__ x,
    const float* __restrict__ Wih1, const float* __restrict__ Whh1,
    const float* __restrict__ bih1, const float* __restrict__ bhh1,
    const float* __restrict__ Whh2,
    const float* __restrict__ bih2, const float* __restrict__ bhh2,
    const float* __restrict__ Whh3,
    const float* __restrict__ bih3, const float* __restrict__ bhh3,
    unsigned* __restrict__ h1r0, unsigned* __restrict__ h2r0,
    unsigned* __restrict__ h3r0, unsigned* __restrict__ cnt,
    unsigned* __restrict__ h1rows, unsigned* __restrict__ h2rows,
    unsigned* __restrict__ h3rows,
    float* __restrict__ xw2, float* __restrict__ xw3,
    const unsigned short* __restrict__ wih2h, const unsigned short* __restrict__ wih2l,
    const unsigned short* __restrict__ wih3h, const unsigned short* __restrict__ wih3l)
{
  __shared__ __align__(16) char smem[32768];
  unsigned* ready1 = cnt + 0;    // tgt 336
  unsigned* done2  = cnt + 16;   // tgt 32
  unsigned* ready2 = cnt + 32;   // tgt 256
  unsigned* done3  = cnt + 48;   // tgt 8
  const int wg = blockIdx.x;
  const int widx = threadIdx.x >> 6, lane = threadIdx.x & 63;

  if (wg < 84) {
    // -------- lstm1 --------
    const int c = wg / 4, sub = wg % 4;
    const int gwv = sub * 4 + widx;
    const int u16i = lane & 15, g = lane >> 4;
    const int grow = g * 256 + gwv * 16 + u16i;

    const f4v* wsrc = (const f4v*)(Whh1 + (size_t)grow * 256);
    const f4v* xsrc = (const f4v*)(Wih1 + (size_t)grow * 64);
#define DH(i) f4v m##i = wsrc[i];
#define DX(i) f4v n##i = xsrc[i];
    L64(DH)
    L16(DX)
#undef DH
#undef DX
    const float bias = bih1[grow] + bhh1[grow];

    float* xls = (float*)smem;
    float* hbb = (float*)(smem + 1024);
    float* const xq = xls + widx * 64;
    float* const hb0 = hbb + widx * 512;

    float cst = 0.0f;
    float xpre = x[(size_t)lane * 21 + c];

    for (int t = 0; t < T_STEPS; ++t) {
      xq[lane] = xpre;
      if (t + 1 < T_STEPS) xpre = x[(size_t)(t + 1) * 1344 + lane * 21 + c];
      const unsigned* src = t ? h1rows + (size_t)(t - 1) * 5376 + c * 256
                              : h1r0 + c * 256;
      unsigned cv[4];
      poll_sent<4>(src, lane, cv);
      float* hb = hb0 + (t & 1) * 256;
      hb[lane]       = unpackhl(cv[0]);
      hb[64 + lane]  = unpackhl(cv[1]);
      hb[128 + lane] = unpackhl(cv[2]);
      hb[192 + lane] = unpackhl(cv[3]);
      float a0 = 0, a1 = 0, a2 = 0, a3 = 0;
#define FH(i) { f4v h4 = *(const f4v*)&hb[4 * i]; \
  a0 = fmaf(m##i[0], h4[0], a0); a1 = fmaf(m##i[1], h4[1], a1); \
  a2 = fmaf(m##i[2], h4[2], a2); a3 = fmaf(m##i[3], h4[3], a3); }
#define FX(i) { f4v x4 = *(const f4v*)&xq[4 * i]; \
  a0 = fmaf(n##i[0], x4[0], a0); a1 = fmaf(n##i[1], x4[1], a1); \
  a2 = fmaf(n##i[2], x4[2], a2); a3 = fmaf(n##i[3], x4[3], a3); }
      L64(FH)
      L16(FX)
#undef FH
#undef FX
      float z = (a0 + a1) + (a2 + a3) + bias;
      float zi = __shfl(z, u16i);
      float zf = __shfl(z, 16 + u16i);
      float zg = __shfl(z, 32 + u16i);
      float zo = __shfl(z, 48 + u16i);
      if (lane < 16) {
        float cn = sigm(zf) * cst + sigm(zi) * tanh_f(zg);
        float hn = sigm(zo) * tanh_f(cn);
        cst = cn;
        st_agent32(&h1rows[(size_t)t * 5376 + c * 256 + gwv * 16 + lane], packhl(hn));
      }
      if ((t & 127) == 127) {
        VMCNT0();
        if (lane == 0) ctr_add(&ready1[t >> 7]);
      }
    }
  } else if (wg < 148) {
    // -------- lstm2 (xw2 already contains bih2+bhh2) --------
    const int gw = (wg - 84) * 4 + widx;
    const int q = lane >> 4, r4 = lane & 15;
    const int u = r4 & 3, g = r4 >> 2;
    const int grow = g * 1024 + gw * 4 + u;

    const f4v* wsrc = (const f4v*)(Whh2 + (size_t)grow * 1024 + q * 256);
#define DW(i) f4v w##i = wsrc[i];
    L64(DW)
#undef DW

    float* hs = (float*)smem;                  // [2][1040]
    float cst = 0.0f;
    float xwn = 0.0f;

    for (int t = 0; t < T_STEPS; ++t) {
      float xwv;
      if ((t & 127) == 0) {
        poll_ctr(&done2[t >> 7], 32);
        xwv = xw2[(size_t)t * 4096 + grow];
      } else xwv = xwn;
      float* hsb = hs + (t & 1) * 1040;
      if (widx == 0) {
        const unsigned* src = t ? h2rows + (size_t)(t - 1) * 1024 : h2r0;
        unsigned cv[16];
        poll_sent<16>(src, lane, cv);
#pragma unroll
        for (int k = 0; k < 16; ++k)
          hsb[(k >> 2) * 260 + (k & 3) * 64 + lane] = unpackhl(cv[k]);
      }
      __syncthreads();
      const float* qreg = hsb + q * 260;
      float a0 = 0, a1 = 0, a2 = 0, a3 = 0;
#define FW(i) { f4v h4 = *(const f4v*)&qreg[4 * i]; \
  a0 = fmaf(w##i[0], h4[0], a0); a1 = fmaf(w##i[1], h4[1], a1); \
  a2 = fmaf(w##i[2], h4[2], a2); a3 = fmaf(w##i[3], h4[3], a3); }
      L64(FW)
#undef FW
      float z = (a0 + a1) + (a2 + a3);
      z += __shfl_xor(z, 16);
      z += __shfl_xor(z, 32);
      z += xwv;
      float zi  = __shfl(z, u);
      float zf  = __shfl(z, 4 + u);
      float zg2 = __shfl(z, 8 + u);
      float zo  = __shfl(z, 12 + u);
      if (lane < 4) {
        float cn = sigm(zf) * cst + sigm(zi) * tanh_f(zg2);
        float hn = sigm(zo) * tanh_f(cn);
        cst = cn;
        st_agent32(&h2rows[(size_t)t * 1024 + gw * 4 + lane], packhl(hn));
      }
      if ((t & 127) == 127) {
        VMCNT0();
        if (lane == 0) ctr_add(&ready2[t >> 7]);
      }
      if (t + 1 < T_STEPS && ((t + 1) & 127) != 0)
        xwn = xw2[(size_t)(t + 1) * 4096 + grow];
    }
  } else if (wg < 152) {
    // -------- lstm3 (xw3 already contains bih3+bhh3) --------
    const int gw = (wg - 148) * 4 + widx;
    const int u16i = lane & 15, g = lane >> 4;
    const int grow = g * 256 + gw * 16 + u16i;

    const f4v* wsrc = (const f4v*)(Whh3 + (size_t)grow * 256);
#define DW(i) f4v w##i = wsrc[i];
    L64(DW)
#undef DW

    float* hbb = (float*)smem;
    float* const hb0 = hbb + widx * 512;
    float cst = 0.0f;
    float xwn = 0.0f;

    for (int t = 0; t < T_STEPS; ++t) {
      float xwv;
      if ((t & 127) == 0) {
        poll_ctr(&done3[t >> 7], 8);
        xwv = xw3[(size_t)t * 1024 + grow];
      } else xwv = xwn;
      const unsigned* src = t ? h3rows + (size_t)(t - 1) * 256 : h3r0;
      unsigned cv[4];
      poll_sent<4>(src, lane, cv);
      float* hb = hb0 + (t & 1) * 256;
      hb[lane]       = __uint_as_float(cv[0]);
      hb[64 + lane]  = __uint_as_float(cv[1]);
      hb[128 + lane] = __uint_as_float(cv[2]);
      hb[192 + lane] = __uint_as_float(cv[3]);
      float a0 = 0, a1 = 0, a2 = 0, a3 = 0;
#define FW(i) { f4v h4 = *(const f4v*)&hb[4 * i]; \
  a0 = fmaf(w##i[0], h4[0], a0); a1 = fmaf(w##i[1], h4[1], a1); \
  a2 = fmaf(w##i[2], h4[2], a2); a3 = fmaf(w##i[3], h4[3], a3); }
      L64(FW)
#undef FW
      float z = (a0 + a1) + (a2 + a3) + xwv;
      float zi = __shfl(z, u16i);
      float zf = __shfl(z, 16 + u16i);
      float zg = __shfl(z, 32 + u16i);
      float zo = __shfl(z, 48 + u16i);
      if (lane < 16) {
        float cn = sigm(zf) * cst + sigm(zi) * tanh_f(zg);
        float hn = sigm(zo) * tanh_f(cn);
        cst = cn;
        st_agent32(&h3rows[(size_t)t * 256 + gw * 16 + lane], __float_as_uint(hn));
      }
      if (t + 1 < T_STEPS && ((t + 1) & 127) != 0)
        xwn = xw3[(size_t)(t + 1) * 1024 + grow];
    }
  } else if (wg < 206) {
    // -------- gemm2 pool --------
    const int pw = wg - 152;
    for (int i = pw; i < 512; i += 54) {
      int tm = i >> 5, tn = i & 31;
      poll_ctr(&ready1[tm], 336);
      gemm_tile_packed(h1rows, wih2h, wih2l, bih2, bhh2,
                       (unsigned*)xw2, tm, tn, 5376, 4096, smem);
      VMCNT0();
      __syncthreads();
      if (threadIdx.x == 0) ctr_add(&done2[tm]);
      __syncthreads();
    }
  } else {
    // -------- gemm3 pool --------
    const int pw = wg - 206;
    for (int i = pw; i < 128; i += 14) {
      int tm = i >> 3, tn = i & 7;
      poll_ctr(&ready2[tm], 256);
      gemm_tile_packed(h2rows, wih3h, wih3l, bih3, bhh3,
                       (unsigned*)xw3, tm, tn, 1024, 1024, smem);
      VMCNT0();
      __syncthreads();
      if (threadIdx.x == 0) ctr_add(&done3[tm]);
      __syncthreads();
    }
  }
}

// ---------------------------------------------------------------------------
__global__ void split_kernel(const float* __restrict__ src,
                             unsigned short* __restrict__ hi,
                             unsigned short* __restrict__ lo, int n) {
  int i = blockIdx.x * 256 + threadIdx.x;
  if (i < n) {
    float v = src[i];
    unsigned short hb = f2bf(v);
    hi[i] = hb;
    lo[i] = f2bf(v - bf2f(hb));
  }
}

__global__ void fc_kernel(const float* __restrict__ h3, const float* __restrict__ Wfc,
                          const float* __restrict__ bfc, float* __restrict__ out) {
  int t = blockIdx.x, m = threadIdx.x;
  if (m < 21) {
    const float* hp = h3 + (size_t)t * 256;
    const float* wp = Wfc + m * 256;
    float a = 0.0f;
#pragma unroll 8
    for (int j = 0; j < 256; ++j) a = fmaf(wp[j], hp[j], a);
    out[t * 21 + m] = a + bfc[m];
  }
}

// ---------------------------------------------------------------------------
extern "C" void kernel_launch(void* const* d_in, const int* in_sizes, int n_in,
                              void* d_out, int out_size, void* d_ws, size_t ws_size,
                              hipStream_t stream) {
  const float* x    = (const float*)d_in[0];
  const float* Wih1 = (const float*)d_in[1];
  const float* Whh1 = (const float*)d_in[2];
  const float* bih1 = (const float*)d_in[3];
  const float* bhh1 = (const float*)d_in[4];
  const float* Wih2 = (const float*)d_in[5];
  const float* Whh2 = (const float*)d_in[6];
  const float* bih2 = (const float*)d_in[7];
  const float* bhh2 = (const float*)d_in[8];
  const float* Wih3 = (const float*)d_in[9];
  const float* Whh3 = (const float*)d_in[10];
  const float* bih3 = (const float*)d_in[11];
  const float* bhh3 = (const float*)d_in[12];
  const float* Wfc  = (const float*)d_in[13];
  const float* bfc  = (const float*)d_in[14];
  float* out = (float*)d_out;

  const size_t WS_NEEDED = 188776448;
  if (ws_size < WS_NEEDED) return;
  char* ws = (char*)d_ws;
  unsigned* h1r0 = (unsigned*)(ws + 0);
  unsigned* h2r0 = (unsigned*)(ws + 21504);
  unsigned* h3r0 = (unsigned*)(ws + 25600);
  unsigned* cnt  = (unsigned*)(ws + 26624);
  unsigned* h1rows = (unsigned*)(ws + 32768);
  unsigned* h2rows = (unsigned*)(ws + 44072960);
  unsigned* h3rows = (unsigned*)(ws + 52461568);
  float* xw2 = (float*)(ws + 54558720);
  float* xw3 = (float*)(ws + 88113152);
  unsigned short* wih2h = (unsigned short*)(ws + 96501760);
  unsigned short* wih2l = (unsigned short*)(ws + 140541952);
  unsigned short* wih3h = (unsigned short*)(ws + 184582144);
  unsigned short* wih3l = (unsigned short*)(ws + 186679296);

  hipMemsetAsync(ws, 0, 32768, stream);
  hipMemsetAsync(ws + 32768, 0xFF, 54525952, stream);

  const int nW2 = 4096 * 5376;
  split_kernel<<<(nW2 + 255) / 256, 256, 0, stream>>>(Wih2, wih2h, wih2l, nW2);
  const int nW3 = 1024 * 1024;
  split_kernel<<<(nW3 + 255) / 256, 256, 0, stream>>>(Wih3, wih3h, wih3l, nW3);

  mega_kernel<<<220, 256, 0, stream>>>(
      x, Wih1, Whh1, bih1, bhh1,
      Whh2, bih2, bhh2, Whh3, bih3, bhh3,
      h1r0, h2r0, h3r0, cnt,
      h1rows, h2rows, h3rows, xw2, xw3,
      wih2h, wih2l, wih3h, wih3l);

  fc_kernel<<<2048, 64, 0, stream>>>((const float*)h3rows, Wfc, bfc, out);
}

// Round 6
// 9738.061 us; speedup vs baseline: 3.3887x; 1.0145x over previous
//
#include <hip/hip_runtime.h>

// ============================================================================
// 3-layer stacked LSTM (T=2048), MI355X — round 6.
// r5 pipeline + fast polls: inline-asm global_load_dwordx4 sc0 sc1 with a
// single s_waitcnt per poll round (was: serialized per-atomic-load waits).
// lstm2 is now fully wave-autonomous (no __syncthreads in any LSTM step loop).
// Roles by blockIdx (220 WGs, all co-resident):
//   [0,84)   lstm1 : 21 ch x 4 WG x 4 waves; lane = full gate row in regs
//   [84,148) lstm2 : 64 WG; wave owns 4 units, lane = quarter-row (256 f32)
//   [148,152)lstm3 : 4 WG; lane = full gate row (256 f32)
//   [152,206)gemm2 pool (54 WG): xw2 tiles, split-bf16 MFMA, packed-u32 A
//   [206,220)gemm3 pool (14 WG): xw3 tiles
// h history: packed (bf16hi|bf16lo) u32 agent stores into [2048]-row buffers
// pre-filled 0xFFFFFFFF; consumers poll != SENT. Tile counters gate bulk xw.
// ============================================================================

#define T_STEPS 2048
#define SENT 0xFFFFFFFFu

using f4v   = __attribute__((ext_vector_type(4))) float;
using s8v   = __attribute__((ext_vector_type(8))) short;
using u16x8 = __attribute__((ext_vector_type(8))) unsigned short;
using u32x4 = __attribute__((ext_vector_type(4))) unsigned;

__device__ __forceinline__ unsigned short f2bf(float v) {
  unsigned u = __float_as_uint(v);
  u = (u + 0x7FFFu + ((u >> 16) & 1u)) >> 16;   // RNE
  return (unsigned short)u;
}
__device__ __forceinline__ float bf2f(unsigned short b) {
  return __uint_as_float(((unsigned)b) << 16);
}
__device__ __forceinline__ unsigned packhl(float v) {
  unsigned short hb = f2bf(v);
  unsigned short lb = f2bf(v - bf2f(hb));
  return (((unsigned)hb) << 16) | lb;
}
__device__ __forceinline__ float unpackhl(unsigned p) {
  return __uint_as_float(p & 0xFFFF0000u) + __uint_as_float(p << 16);
}
__device__ __forceinline__ float sigm(float x) { return 1.0f / (1.0f + __expf(-x)); }
__device__ __forceinline__ float tanh_f(float x) {
  float ax = fabsf(x);
  float e = __expf(-2.0f * ax);
  float t = (1.0f - e) / (1.0f + e);
  return copysignf(t, x);
}
__device__ __forceinline__ unsigned ld_agent32(const unsigned* p) {
  return __hip_atomic_load(p, __ATOMIC_RELAXED, __HIP_MEMORY_SCOPE_AGENT);
}
__device__ __forceinline__ void st_agent32(unsigned* p, unsigned v) {
  __hip_atomic_store(p, v, __ATOMIC_RELAXED, __HIP_MEMORY_SCOPE_AGENT);
}
__device__ __forceinline__ void ctr_add(unsigned* p) {
  __hip_atomic_fetch_add(p, 1u, __ATOMIC_RELAXED, __HIP_MEMORY_SCOPE_AGENT);
}
__device__ __forceinline__ void poll_ctr(const unsigned* p, unsigned tgt) {
  unsigned n = 0;
  while (ld_agent32(p) < tgt) {
    if (++n > (1u << 22)) break;               // parachute
    __builtin_amdgcn_s_sleep(4);
  }
}
// One coherent 16B load (bypasses L1/L2, hits LLC), single waitcnt.
__device__ __forceinline__ u32x4 ld16_coh(const unsigned* addr) {
  u32x4 c;
  asm volatile("global_load_dwordx4 %0, %1, off sc0 sc1\n\t"
               "s_waitcnt vmcnt(0)"
               : "=&v"(c) : "v"(addr) : "memory");
  return c;
}
#define VMCNT0() asm volatile("s_waitcnt vmcnt(0)" ::: "memory")

#define L16(M) M(0) M(1) M(2) M(3) M(4) M(5) M(6) M(7) M(8) M(9) M(10) M(11) \
  M(12) M(13) M(14) M(15)
#define L64(M) L16(M) M(16) M(17) M(18) M(19) M(20) M(21) M(22) M(23) M(24) \
  M(25) M(26) M(27) M(28) M(29) M(30) M(31) M(32) M(33) M(34) M(35) M(36) \
  M(37) M(38) M(39) M(40) M(41) M(42) M(43) M(44) M(45) M(46) M(47) M(48) \
  M(49) M(50) M(51) M(52) M(53) M(54) M(55) M(56) M(57) M(58) M(59) M(60) \
  M(61) M(62) M(63)

// ---------------------------------------------------------------------------
// split-bf16 GEMM tile, A = packed (hi|lo) u32, C = A*B^T + (b1+b2), atomic C
// ---------------------------------------------------------------------------
__device__ __forceinline__ void unpack8(u32x4 a, u32x4 b, u16x8& hi, u16x8& lo) {
#pragma unroll
  for (int j = 0; j < 4; ++j) {
    hi[j]     = (unsigned short)(a[j] >> 16);
    lo[j]     = (unsigned short)(a[j] & 0xFFFFu);
    hi[4 + j] = (unsigned short)(b[j] >> 16);
    lo[4 + j] = (unsigned short)(b[j] & 0xFFFFu);
  }
}

__device__ void gemm_tile_packed(
    const unsigned* __restrict__ Ap, const unsigned short* __restrict__ Bh,
    const unsigned short* __restrict__ Bl, const float* __restrict__ b1,
    const float* __restrict__ b2, unsigned* __restrict__ C,
    int tm, int tn, int K, int N, char* smem)
{
  unsigned short* lds = (unsigned short*)smem;   // Ah|Al|Bh|Bl planes [128][32]
  const size_t m0 = (size_t)tm * 128, n0 = (size_t)tn * 128;
  const int tid = threadIdx.x, lane = tid & 63, w = tid >> 6;
  const int wr = w >> 1, wc = w & 1;
  const int srow = tid >> 2, sc8 = (tid & 3) * 8;

  const unsigned* pA = Ap + m0 * K;
  const unsigned short* pBh = Bh + n0 * K;
  const unsigned short* pBl = Bl + n0 * K;

  f4v acc[4][4];
#pragma unroll
  for (int i = 0; i < 4; ++i)
#pragma unroll
    for (int j = 0; j < 4; ++j) acc[i][j] = f4v{0.f, 0.f, 0.f, 0.f};

  u32x4 a00, a01, a10, a11;
  u16x8 s4, s5, s6, s7;
#define LOADK(k0)                                                           \
  a00 = *(const u32x4*)(pA + (size_t)srow * K + (k0) + sc8);                \
  a01 = *(const u32x4*)(pA + (size_t)srow * K + (k0) + sc8 + 4);            \
  a10 = *(const u32x4*)(pA + (size_t)(srow + 64) * K + (k0) + sc8);         \
  a11 = *(const u32x4*)(pA + (size_t)(srow + 64) * K + (k0) + sc8 + 4);     \
  s4 = *(const u16x8*)(pBh + (size_t)srow * K + (k0) + sc8);                \
  s5 = *(const u16x8*)(pBh + (size_t)(srow + 64) * K + (k0) + sc8);         \
  s6 = *(const u16x8*)(pBl + (size_t)srow * K + (k0) + sc8);                \
  s7 = *(const u16x8*)(pBl + (size_t)(srow + 64) * K + (k0) + sc8);

  LOADK(0);
  const int fr = lane & 15, fko = (lane >> 4) * 8;
  for (int k0 = 0; k0 < K; k0 += 32) {
    u16x8 h0, l0, h1, l1;
    unpack8(a00, a01, h0, l0);
    unpack8(a10, a11, h1, l1);
    *(u16x8*)&lds[0     +  srow       * 32 + sc8] = h0;
    *(u16x8*)&lds[0     + (srow + 64) * 32 + sc8] = h1;
    *(u16x8*)&lds[4096  +  srow       * 32 + sc8] = l0;
    *(u16x8*)&lds[4096  + (srow + 64) * 32 + sc8] = l1;
    *(u16x8*)&lds[8192  +  srow       * 32 + sc8] = s4;
    *(u16x8*)&lds[8192  + (srow + 64) * 32 + sc8] = s5;
    *(u16x8*)&lds[12288 +  srow       * 32 + sc8] = s6;
    *(u16x8*)&lds[12288 + (srow + 64) * 32 + sc8] = s7;
    __syncthreads();
    if (k0 + 32 < K) { LOADK(k0 + 32); }
    s8v afh[4], afl[4], bfh[4], bfl[4];
#pragma unroll
    for (int i = 0; i < 4; ++i) {
      int ar = (64 * wr + 16 * i + fr) * 32 + fko;
      int br = (64 * wc + 16 * i + fr) * 32 + fko;
      afh[i] = *(const s8v*)&lds[0 + ar];
      afl[i] = *(const s8v*)&lds[4096 + ar];
      bfh[i] = *(const s8v*)&lds[8192 + br];
      bfl[i] = *(const s8v*)&lds[12288 + br];
    }
#pragma unroll
    for (int mi = 0; mi < 4; ++mi)
#pragma unroll
      for (int ni = 0; ni < 4; ++ni) {
        acc[mi][ni] = __builtin_amdgcn_mfma_f32_16x16x32_bf16(afh[mi], bfh[ni], acc[mi][ni], 0, 0, 0);
        acc[mi][ni] = __builtin_amdgcn_mfma_f32_16x16x32_bf16(afh[mi], bfl[ni], acc[mi][ni], 0, 0, 0);
        acc[mi][ni] = __builtin_amdgcn_mfma_f32_16x16x32_bf16(afl[mi], bfh[ni], acc[mi][ni], 0, 0, 0);
      }
    __syncthreads();
  }
#undef LOADK
  const int er = (lane >> 4) * 4, ec = lane & 15;
#pragma unroll
  for (int ni = 0; ni < 4; ++ni) {
    size_t col = n0 + 64 * wc + 16 * ni + ec;
    float bv = b1[col] + b2[col];
#pragma unroll
    for (int mi = 0; mi < 4; ++mi) {
      size_t row = m0 + 64 * wr + 16 * mi + er;
#pragma unroll
      for (int rr = 0; rr < 4; ++rr)
        st_agent32(&C[(row + rr) * N + col], __float_as_uint(acc[mi][ni][rr] + bv));
    }
  }
}

// ---------------------------------------------------------------------------
// mega kernel
// ---------------------------------------------------------------------------
__global__ __launch_bounds__(256, 1) void mega_kernel(
    const float* __restrict__ x,
    const float* __restrict__ Wih1, const float* __restrict__ Whh1,
    const float* __restrict__ bih1, const float* __restrict__ bhh1,
    const float* __restrict__ Whh2,
    const float* __restrict__ bih2, const float* __restrict__ bhh2,
    const float* __restrict__ Whh3,
    const float* __restrict__ bih3, const float* __restrict__ bhh3,
    unsigned* __restrict__ h1r0, unsigned* __restrict__ h2r0,
    unsigned* __restrict__ h3r0, unsigned* __restrict__ cnt,
    unsigned* __restrict__ h1rows, unsigned* __restrict__ h2rows,
    unsigned* __restrict__ h3rows,
    float* __restrict__ xw2, float* __restrict__ xw3,
    const unsigned short* __restrict__ wih2h, const unsigned short* __restrict__ wih2l,
    const unsigned short* __restrict__ wih3h, const unsigned short* __restrict__ wih3l)
{
  __shared__ __align__(16) char smem[32768];
  unsigned* ready1 = cnt + 0;    // tgt 336
  unsigned* done2  = cnt + 16;   // tgt 32
  unsigned* ready2 = cnt + 32;   // tgt 256
  unsigned* done3  = cnt + 48;   // tgt 8
  const int wg = blockIdx.x;
  const int widx = threadIdx.x >> 6, lane = threadIdx.x & 63;

  if (wg < 84) {
    // -------- lstm1: wave-autonomous; lane = full gate row ------------------
    const int c = wg / 4, sub = wg % 4;
    const int gwv = sub * 4 + widx;            // 0..15
    const int u16i = lane & 15, g = lane >> 4;
    const int grow = g * 256 + gwv * 16 + u16i;

    const f4v* wsrc = (const f4v*)(Whh1 + (size_t)grow * 256);
    const f4v* xsrc = (const f4v*)(Wih1 + (size_t)grow * 64);
#define DH(i) f4v m##i = wsrc[i];
#define DX(i) f4v n##i = xsrc[i];
    L64(DH)
    L16(DX)
#undef DH
#undef DX
    const float bias = bih1[grow] + bhh1[grow];

    // wave-private: h[256] + x[64]
    float* const hb = (float*)smem + widx * 320;
    float* const xq = hb + 256;

    float cst = 0.0f;
    float xpre = x[(size_t)lane * 21 + c];

    for (int t = 0; t < T_STEPS; ++t) {
      xq[lane] = xpre;
      if (t + 1 < T_STEPS) xpre = x[(size_t)(t + 1) * 1344 + lane * 21 + c];
      const unsigned* src = t ? h1rows + (size_t)(t - 1) * 5376 + c * 256
                              : h1r0 + c * 256;
      const unsigned* addr = src + 4 * lane;
      u32x4 c0;
      unsigned n = 0;
      for (;;) {
        c0 = ld16_coh(addr);
        bool ok = (c0[0] != SENT) && (c0[1] != SENT) &&
                  (c0[2] != SENT) && (c0[3] != SENT);
        if (ok || ++n > (1u << 18)) break;     // parachute
      }
      *(f4v*)&hb[4 * lane] = f4v{unpackhl(c0[0]), unpackhl(c0[1]),
                                 unpackhl(c0[2]), unpackhl(c0[3])};
      float a0 = 0, a1 = 0, a2 = 0, a3 = 0;
#define FH(i) { f4v h4 = *(const f4v*)&hb[4 * i]; \
  a0 = fmaf(m##i[0], h4[0], a0); a1 = fmaf(m##i[1], h4[1], a1); \
  a2 = fmaf(m##i[2], h4[2], a2); a3 = fmaf(m##i[3], h4[3], a3); }
#define FX(i) { f4v x4 = *(const f4v*)&xq[4 * i]; \
  a0 = fmaf(n##i[0], x4[0], a0); a1 = fmaf(n##i[1], x4[1], a1); \
  a2 = fmaf(n##i[2], x4[2], a2); a3 = fmaf(n##i[3], x4[3], a3); }
      L64(FH)
      L16(FX)
#undef FH
#undef FX
      float z = (a0 + a1) + (a2 + a3) + bias;
      float zi = __shfl(z, u16i);
      float zf = __shfl(z, 16 + u16i);
      float zg = __shfl(z, 32 + u16i);
      float zo = __shfl(z, 48 + u16i);
      if (lane < 16) {
        float cn = sigm(zf) * cst + sigm(zi) * tanh_f(zg);
        float hn = sigm(zo) * tanh_f(cn);
        cst = cn;
        st_agent32(&h1rows[(size_t)t * 5376 + c * 256 + gwv * 16 + lane], packhl(hn));
      }
      if ((t & 127) == 127) {
        VMCNT0();
        if (lane == 0) ctr_add(&ready1[t >> 7]);
      }
    }
  } else if (wg < 148) {
    // -------- lstm2: wave-autonomous; lane = quarter-row --------------------
    const int gw = (wg - 84) * 4 + widx;       // 0..255
    const int q = lane >> 4, r4 = lane & 15;
    const int u = r4 & 3, g = r4 >> 2;
    const int grow = g * 1024 + gw * 4 + u;

    const f4v* wsrc = (const f4v*)(Whh2 + (size_t)grow * 1024 + q * 256);
#define DW(i) f4v w##i = wsrc[i];
    L64(DW)
#undef DW

    // wave-private staging: 4 quarters x 260 (skew 4 f32 keeps reads clean)
    float* const wls = (float*)smem + widx * 1040;
    const float* const qreg = wls + q * 260;

    float cst = 0.0f;
    float xwn = 0.0f;

    for (int t = 0; t < T_STEPS; ++t) {
      float xwv;
      if ((t & 127) == 0) {
        poll_ctr(&done2[t >> 7], 32);
        xwv = xw2[(size_t)t * 4096 + grow];
      } else xwv = xwn;
      {
        const unsigned* src = t ? h2rows + (size_t)(t - 1) * 1024 : h2r0;
        const unsigned* addr = src + 4 * lane;
        u32x4 c0, c1, c2, c3;
        unsigned n = 0;
        for (;;) {
          asm volatile(
              "global_load_dwordx4 %0, %4, off sc0 sc1\n\t"
              "global_load_dwordx4 %1, %4, off offset:1024 sc0 sc1\n\t"
              "global_load_dwordx4 %2, %4, off offset:2048 sc0 sc1\n\t"
              "global_load_dwordx4 %3, %4, off offset:3072 sc0 sc1\n\t"
              "s_waitcnt vmcnt(0)"
              : "=&v"(c0), "=&v"(c1), "=&v"(c2), "=&v"(c3)
              : "v"(addr) : "memory");
          bool ok = true;
#pragma unroll
          for (int j = 0; j < 4; ++j)
            ok = ok && (c0[j] != SENT) && (c1[j] != SENT) &&
                       (c2[j] != SENT) && (c3[j] != SENT);
          if (ok || ++n > (1u << 18)) break;   // parachute
        }
        // value 256k+4*lane+j -> wls[k*260 + 4*lane + j]
        *(f4v*)&wls[0 * 260 + 4 * lane] = f4v{unpackhl(c0[0]), unpackhl(c0[1]), unpackhl(c0[2]), unpackhl(c0[3])};
        *(f4v*)&wls[1 * 260 + 4 * lane] = f4v{unpackhl(c1[0]), unpackhl(c1[1]), unpackhl(c1[2]), unpackhl(c1[3])};
        *(f4v*)&wls[2 * 260 + 4 * lane] = f4v{unpackhl(c2[0]), unpackhl(c2[1]), unpackhl(c2[2]), unpackhl(c2[3])};
        *(f4v*)&wls[3 * 260 + 4 * lane] = f4v{unpackhl(c3[0]), unpackhl(c3[1]), unpackhl(c3[2]), unpackhl(c3[3])};
      }
      float a0 = 0, a1 = 0, a2 = 0, a3 = 0;
#define FW(i) { f4v h4 = *(const f4v*)&qreg[4 * i]; \
  a0 = fmaf(w##i[0], h4[0], a0); a1 = fmaf(w##i[1], h4[1], a1); \
  a2 = fmaf(w##i[2], h4[2], a2); a3 = fmaf(w##i[3], h4[3], a3); }
      L64(FW)
#undef FW
      float z = (a0 + a1) + (a2 + a3);
      z += __shfl_xor(z, 16);
      z += __shfl_xor(z, 32);
      z += xwv;
      float zi  = __shfl(z, u);
      float zf  = __shfl(z, 4 + u);
      float zg2 = __shfl(z, 8 + u);
      float zo  = __shfl(z, 12 + u);
      if (lane < 4) {
        float cn = sigm(zf) * cst + sigm(zi) * tanh_f(zg2);
        float hn = sigm(zo) * tanh_f(cn);
        cst = cn;
        st_agent32(&h2rows[(size_t)t * 1024 + gw * 4 + lane], packhl(hn));
      }
      if ((t & 127) == 127) {
        VMCNT0();
        if (lane == 0) ctr_add(&ready2[t >> 7]);
      }
      if (t + 1 < T_STEPS && ((t + 1) & 127) != 0)
        xwn = xw2[(size_t)(t + 1) * 4096 + grow];
    }
  } else if (wg < 152) {
    // -------- lstm3: wave-autonomous; lane = full gate row ------------------
    const int gw = (wg - 148) * 4 + widx;      // 0..15
    const int u16i = lane & 15, g = lane >> 4;
    const int grow = g * 256 + gw * 16 + u16i;

    const f4v* wsrc = (const f4v*)(Whh3 + (size_t)grow * 256);
#define DW(i) f4v w##i = wsrc[i];
    L64(DW)
#undef DW

    float* const hb = (float*)smem + widx * 256;
    float cst = 0.0f;
    float xwn = 0.0f;

    for (int t = 0; t < T_STEPS; ++t) {
      float xwv;
      if ((t & 127) == 0) {
        poll_ctr(&done3[t >> 7], 8);
        xwv = xw3[(size_t)t * 1024 + grow];
      } else xwv = xwn;
      const unsigned* src = t ? h3rows + (size_t)(t - 1) * 256 : h3r0;
      const unsigned* addr = src + 4 * lane;
      u32x4 c0;
      unsigned n = 0;
      for (;;) {
        c0 = ld16_coh(addr);
        bool ok = (c0[0] != SENT) && (c0[1] != SENT) &&
                  (c0[2] != SENT) && (c0[3] != SENT);
        if (ok || ++n > (1u << 18)) break;
      }
      *(f4v*)&hb[4 * lane] = f4v{__uint_as_float(c0[0]), __uint_as_float(c0[1]),
                                 __uint_as_float(c0[2]), __uint_as_float(c0[3])};
      float a0 = 0, a1 = 0, a2 = 0, a3 = 0;
#define FW(i) { f4v h4 = *(const f4v*)&hb[4 * i]; \
  a0 = fmaf(w##i[0], h4[0], a0); a1 = fmaf(w##i[1], h4[1], a1); \
  a2 = fmaf(w##i[2], h4[2], a2); a3 = fmaf(w##i[3], h4[3], a3); }
      L64(FW)
#undef FW
      float z = (a0 + a1) + (a2 + a3) + xwv;
      float zi = __shfl(z, u16i);
      float zf = __shfl(z, 16 + u16i);
      float zg = __shfl(z, 32 + u16i);
      float zo = __shfl(z, 48 + u16i);
      if (lane < 16) {
        float cn = sigm(zf) * cst + sigm(zi) * tanh_f(zg);
        float hn = sigm(zo) * tanh_f(cn);
        cst = cn;
        st_agent32(&h3rows[(size_t)t * 256 + gw * 16 + lane], __float_as_uint(hn));
      }
      if (t + 1 < T_STEPS && ((t + 1) & 127) != 0)
        xwn = xw3[(size_t)(t + 1) * 1024 + grow];
    }
  } else if (wg < 206) {
    // -------- gemm2 pool --------
    const int pw = wg - 152;
    for (int i = pw; i < 512; i += 54) {
      int tm = i >> 5, tn = i & 31;
      poll_ctr(&ready1[tm], 336);
      gemm_tile_packed(h1rows, wih2h, wih2l, bih2, bhh2,
                       (unsigned*)xw2, tm, tn, 5376, 4096, smem);
      VMCNT0();
      __syncthreads();
      if (threadIdx.x == 0) ctr_add(&done2[tm]);
      __syncthreads();
    }
  } else {
    // -------- gemm3 pool --------
    const int pw = wg - 206;
    for (int i = pw; i < 128; i += 14) {
      int tm = i >> 3, tn = i & 7;
      poll_ctr(&ready2[tm], 256);
      gemm_tile_packed(h2rows, wih3h, wih3l, bih3, bhh3,
                       (unsigned*)xw3, tm, tn, 1024, 1024, smem);
      VMCNT0();
      __syncthreads();
      if (threadIdx.x == 0) ctr_add(&done3[tm]);
      __syncthreads();
    }
  }
}

// ---------------------------------------------------------------------------
__global__ void split_kernel(const float* __restrict__ src,
                             unsigned short* __restrict__ hi,
                             unsigned short* __restrict__ lo, int n) {
  int i = blockIdx.x * 256 + threadIdx.x;
  if (i < n) {
    float v = src[i];
    unsigned short hb = f2bf(v);
    hi[i] = hb;
    lo[i] = f2bf(v - bf2f(hb));
  }
}

__global__ void fc_kernel(const float* __restrict__ h3, const float* __restrict__ Wfc,
                          const float* __restrict__ bfc, float* __restrict__ out) {
  int t = blockIdx.x, m = threadIdx.x;
  if (m < 21) {
    const float* hp = h3 + (size_t)t * 256;
    const float* wp = Wfc + m * 256;
    float a = 0.0f;
#pragma unroll 8
    for (int j = 0; j < 256; ++j) a = fmaf(wp[j], hp[j], a);
    out[t * 21 + m] = a + bfc[m];
  }
}

// ---------------------------------------------------------------------------
extern "C" void kernel_launch(void* const* d_in, const int* in_sizes, int n_in,
                              void* d_out, int out_size, void* d_ws, size_t ws_size,
                              hipStream_t stream) {
  const float* x    = (const float*)d_in[0];
  const float* Wih1 = (const float*)d_in[1];
  const float* Whh1 = (const float*)d_in[2];
  const float* bih1 = (const float*)d_in[3];
  const float* bhh1 = (const float*)d_in[4];
  const float* Wih2 = (const float*)d_in[5];
  const float* Whh2 = (const float*)d_in[6];
  const float* bih2 = (const float*)d_in[7];
  const float* bhh2 = (const float*)d_in[8];
  const float* Wih3 = (const float*)d_in[9];
  const float* Whh3 = (const float*)d_in[10];
  const float* bih3 = (const float*)d_in[11];
  const float* bhh3 = (const float*)d_in[12];
  const float* Wfc  = (const float*)d_in[13];
  const float* bfc  = (const float*)d_in[14];
  float* out = (float*)d_out;

  const size_t WS_NEEDED = 188776448;
  if (ws_size < WS_NEEDED) return;
  char* ws = (char*)d_ws;
  unsigned* h1r0 = (unsigned*)(ws + 0);
  unsigned* h2r0 = (unsigned*)(ws + 21504);
  unsigned* h3r0 = (unsigned*)(ws + 25600);
  unsigned* cnt  = (unsigned*)(ws + 26624);
  unsigned* h1rows = (unsigned*)(ws + 32768);
  unsigned* h2rows = (unsigned*)(ws + 44072960);
  unsigned* h3rows = (unsigned*)(ws + 52461568);
  float* xw2 = (float*)(ws + 54558720);
  float* xw3 = (float*)(ws + 88113152);
  unsigned short* wih2h = (unsigned short*)(ws + 96501760);
  unsigned short* wih2l = (unsigned short*)(ws + 140541952);
  unsigned short* wih3h = (unsigned short*)(ws + 184582144);
  unsigned short* wih3l = (unsigned short*)(ws + 186679296);

  hipMemsetAsync(ws, 0, 32768, stream);
  hipMemsetAsync(ws + 32768, 0xFF, 54525952, stream);

  const int nW2 = 4096 * 5376;
  split_kernel<<<(nW2 + 255) / 256, 256, 0, stream>>>(Wih2, wih2h, wih2l, nW2);
  const int nW3 = 1024 * 1024;
  split_kernel<<<(nW3 + 255) / 256, 256, 0, stream>>>(Wih3, wih3h, wih3l, nW3);

  mega_kernel<<<220, 256, 0, stream>>>(
      x, Wih1, Whh1, bih1, bhh1,
      Whh2, bih2, bhh2, Whh3, bih3, bhh3,
      h1r0, h2r0, h3r0, cnt,
      h1rows, h2rows, h3rows, xw2, xw3,
      wih2h, wih2l, wih3h, wih3l);

  fc_kernel<<<2048, 64, 0, stream>>>((const float*)h3rows, Wfc, bfc, out);
}